// Round 2
// baseline (1373.306 us; speedup 1.0000x reference)
//
#include <hip/hip_runtime.h>
#include <stdint.h>

typedef unsigned short u16;
typedef __attribute__((ext_vector_type(8))) short bfrag;   // 8 bf16 = 4 VGPR MFMA operand
typedef __attribute__((ext_vector_type(4))) float f32x4;
typedef __attribute__((ext_vector_type(16))) float f32x16; // 32x32 MFMA accumulator
typedef __attribute__((ext_vector_type(4))) unsigned int u32x4;

#define DEVI __device__ __forceinline__

DEVI float b2f(u16 u){ return __uint_as_float(((uint32_t)u) << 16); }
DEVI u16 f2b(float f){
  uint32_t x = __float_as_uint(f);
  uint32_t r = (x + 0x7fffu + ((x >> 16) & 1u)) >> 16;   // RNE
  return (u16)r;
}
DEVI float silu_f(float v){ return v / (1.0f + __expf(-v)); }
DEVI float lo16(uint32_t w){ return b2f((u16)(w & 0xffffu)); }
DEVI float hi16(uint32_t w){ return b2f((u16)(w >> 16)); }
DEVI uint32_t cvtpk(float lo, float hi){
  uint32_t r;
  asm("v_cvt_pk_bf16_f32 %0, %1, %2" : "=v"(r) : "v"(lo), "v"(hi));
  return r;
}

// ---- weight arena element offsets (bf16 elements) ----
// KJ/DOWN: transposed [N][K] row-major (for k_gemmb).
// Chain weights (JI/UP/BS1/BS2/LIN/AS1/AS2): FRAGMENT-MAJOR for 32x32x16 MFMA:
//   elem idx = ((nb*KS + ks)*64 + lane)*8 + j  holds W[o][k],
//   o = nb*32 + (lane&31), k = ks*16 + (lane>>5)*8 + j   (KS = K/16)
#define OFF_KJ   0
#define OFF_DOWN 16384
#define OFF_JI   24576
#define OFF_UP   122880
#define OFF_BS1  172032
#define OFF_BS2  270336
#define OFF_LIN  368640
#define OFF_AS1  466944
#define OFF_AS2  565248
#define WT_TOTAL 663552

struct TW {
  const float *kj, *down, *ji, *up, *bs1, *bs2, *lin, *as1, *as2;
  u16* dst;
};

// Transpose+convert all weight matrices once. mode 0: [K,N]->[N,K];
// mode 1: frag-major K=128; mode 2: frag-major K=64.
__global__ void __launch_bounds__(256) k_transpose(TW p){
  int id = blockIdx.y;
  const float* src; int K, N, doff, mode;
  if      (id == 0) { src = p.kj;   K = 128; N = 128; doff = OFF_KJ;   mode = 0; }
  else if (id == 1) { src = p.down; K = 128; N = 64;  doff = OFF_DOWN; mode = 0; }
  else if (id < 8)  { int b = id - 2;  src = p.ji  + b*16384; K = 128; N = 128; doff = OFF_JI  + b*16384; mode = 1; }
  else if (id < 14) { int b = id - 8;  src = p.up  + b*8192;  K = 64;  N = 128; doff = OFF_UP  + b*8192;  mode = 2; }
  else if (id < 20) { int b = id - 14; src = p.bs1 + b*16384; K = 128; N = 128; doff = OFF_BS1 + b*16384; mode = 1; }
  else if (id < 26) { int b = id - 20; src = p.bs2 + b*16384; K = 128; N = 128; doff = OFF_BS2 + b*16384; mode = 1; }
  else if (id < 32) { int b = id - 26; src = p.lin + b*16384; K = 128; N = 128; doff = OFF_LIN + b*16384; mode = 1; }
  else if (id < 38) { int b = id - 32; src = p.as1 + b*16384; K = 128; N = 128; doff = OFF_AS1 + b*16384; mode = 1; }
  else              { int b = id - 38; src = p.as2 + b*16384; K = 128; N = 128; doff = OFF_AS2 + b*16384; mode = 1; }
  int idx = blockIdx.x*256 + threadIdx.x;
  if (idx >= K*N) return;
  float v;
  if (mode == 0){
    int n = idx / K, k = idx - n*K;
    v = src[k*N + n];
  } else if (mode == 1){
    int j = idx & 7, lv = (idx >> 3) & 63, ks = (idx >> 9) & 7, nb = idx >> 12;
    int o = nb*32 + (lv & 31), k = ks*16 + (lv >> 5)*8 + j;
    v = src[k*128 + o];
  } else {
    int j = idx & 7, lv = (idx >> 3) & 63, ks = (idx >> 9) & 3, nb = idx >> 11;
    int o = nb*32 + (lv & 31), k = ks*16 + (lv >> 5)*8 + j;
    v = src[k*128 + o];
  }
  p.dst[doff + idx] = f2b(v);
}

// elementwise fp32 -> bf16
__global__ void __launch_bounds__(256) k_f2b(
    const float* __restrict__ src, u16* __restrict__ dst, int n)
{
  int i = blockIdx.x*256 + threadIdx.x;
  if (i < n) dst[i] = f2b(src[i]);
}

// rbf2[e,h] = ((rbf @ W_rbf1) @ W_rbf2)[e,h]
__global__ void __launch_bounds__(256) k_rbf(
    const float* __restrict__ rbf, const float* __restrict__ W1,
    const float* __restrict__ W2, u16* __restrict__ out, int E)
{
  __shared__ float w1s[48];
  __shared__ float w2s[1024];
  for (int i = threadIdx.x; i < 48;   i += 256) w1s[i] = W1[i];
  for (int i = threadIdx.x; i < 1024; i += 256) w2s[i] = W2[i];
  __syncthreads();
  int idx = blockIdx.x*256 + threadIdx.x;
  if (idx >= E*128) return;
  int e = idx >> 7, h = idx & 127;
  float rv[6];
#pragma unroll
  for (int k = 0; k < 6; k++) rv[k] = rbf[e*6 + k];
  float o = 0.f;
#pragma unroll
  for (int j = 0; j < 8; j++){
    float m = 0.f;
#pragma unroll
    for (int k = 0; k < 6; k++) m += rv[k] * w1s[k*8 + j];
    o += m * w2s[j*128 + h];
  }
  out[idx] = f2b(o);
}

// s1[t,0:8] = (sbf @ W_sbf1)[t]
__global__ void __launch_bounds__(256) k_s1(
    const float* __restrict__ sbf, const float* __restrict__ W1,
    float* __restrict__ s1, int T)
{
  __shared__ float w1s[336];
  for (int i = threadIdx.x; i < 336; i += 256) w1s[i] = W1[i];
  __syncthreads();
  int t = blockIdx.x*256 + threadIdx.x;
  if (t >= T) return;
  const float* row = sbf + (size_t)t*42;
  float a[8];
#pragma unroll
  for (int j = 0; j < 8; j++) a[j] = 0.f;
  for (int k = 0; k < 42; k++){
    float sv = row[k];
#pragma unroll
    for (int j = 0; j < 8; j++) a[j] += sv * w1s[k*8 + j];
  }
#pragma unroll
  for (int j = 0; j < 8; j++) s1[(size_t)t*8 + j] = a[j];
}

// one wave per triplet: sbf_e = s1 @ W_sbf2; v = x_kj[idx_kj]*sbf_e; scatter into agg[branch]
__global__ void __launch_bounds__(256) k_triplet(
    const int* __restrict__ idx_kj, const int* __restrict__ idx_ji,
    const int* __restrict__ bt, const float* __restrict__ s1,
    const float* __restrict__ Wsbf2, const u16* __restrict__ xkj,
    float* __restrict__ agg, int T, int E)
{
  int g = blockIdx.x*256 + threadIdx.x;
  int t = g >> 6, lane = g & 63;
  if (t >= T) return;
  int kj = idx_kj[t], ji = idx_ji[t];
  int b = bt[kj] + 1;
  b = b < 0 ? 0 : (b > 5 ? 5 : b);
  float se = 0.f;
#pragma unroll
  for (int j = 0; j < 8; j++) se += s1[(size_t)t*8 + j] * Wsbf2[j*64 + lane];
  float v = b2f(xkj[(size_t)kj*64 + lane]) * se;
  unsafeAtomicAdd(&agg[((size_t)b*E + ji)*64 + lane], v);
}

// agg fp32 -> aggb bf16 slots 0..5, slot 6 = sum (== agg_gen)
__global__ void __launch_bounds__(256) k_cvt(
    const float* __restrict__ agg, u16* __restrict__ aggb, int EI)
{
  int idx = blockIdx.x*256 + threadIdx.x;
  if (idx >= EI) return;
  float s = 0.f;
#pragma unroll
  for (int b = 0; b < 6; b++){
    float v = agg[(size_t)b*EI + idx];
    s += v;
    aggb[(size_t)b*EI + idx] = f2b(v);
  }
  aggb[(size_t)6*EI + idx] = f2b(s);
}

// reduce nsl slices of S into out (fp32)
__global__ void __launch_bounds__(256) k_red(
    const u16* __restrict__ S, const float* __restrict__ alphaP,
    float* __restrict__ out, size_t EH, int nsl, int genLast, int accum)
{
  size_t base = ((size_t)blockIdx.x*256 + threadIdx.x)*4;
  if (base >= EH) return;
  float al = alphaP[0];
  float s0=0,s1=0,s2=0,s3=0;
  for (int c = 0; c < nsl; c++){
    float sc = (genLast && c == nsl-1) ? al : (1.f - al);
    ushort4 v = *(const ushort4*)&S[(size_t)c*EH + base];
    s0 += sc*b2f(v.x); s1 += sc*b2f(v.y); s2 += sc*b2f(v.z); s3 += sc*b2f(v.w);
  }
  float4 o;
  if (accum){
    float4 p = *(const float4*)&out[base];
    o.x = p.x + s0; o.y = p.y + s1; o.z = p.z + s2; o.w = p.w + s3;
  } else {
    o.x = s0; o.y = s1; o.z = s2; o.w = s3;
  }
  *(float4*)&out[base] = o;
}

// ================== batched fused-epilogue MFMA GEMM (pre-chain) ==================
template<int MODE, int N, int K>
__global__ void __launch_bounds__(256) k_gemmb(
    const u16* __restrict__ A, size_t aStr,
    const u16* __restrict__ WTp, int wStr,
    const float* __restrict__ bias, int bStr,
    const u16* __restrict__ aux, size_t xStr,
    u16* __restrict__ out, size_t oStr,
    int cBase, int M)
{
  constexpr int KP = K + 8;
  constexpr int PITCH = N + 4;
  constexpr size_t SW = (size_t)KP*N*2;
  constexpr size_t SE = (size_t)64*PITCH*4;
  constexpr size_t SMEM = SW > SE ? SW : SE;
  __shared__ __attribute__((aligned(16))) char smem[SMEM];
  u16*   wlds = (u16*)smem;
  float* elds = (float*)smem;

  const int tid = threadIdx.x;
  const int sl = blockIdx.y;
  const int c = cBase + sl;
  const int wsel = c < 5 ? c : 5;
  const u16* __restrict__ Ac = A + (size_t)sl*aStr;
  const u16* __restrict__ Wc = WTp + (size_t)wsel*wStr;
  const u16* __restrict__ auxc = aux ? aux + (size_t)sl*xStr : (const u16*)0;
  u16* __restrict__ outc = out + (size_t)sl*oStr;

  constexpr int CH = (N*K)/8;
  for (int ch = tid; ch < CH; ch += 256){
    int n  = ch / (K/8);
    int kc = (ch - n*(K/8))*8;
    *(int4*)&wlds[n*KP + kc] = *(const int4*)&Wc[n*K + kc];
  }
  __syncthreads();

  const int wave = tid >> 6, lane = tid & 63;
  const int lr = lane & 15, lq = lane >> 4;
  const int m0 = blockIdx.x*128 + wave*32;
  constexpr int NBN = N/16;
  f32x4 acc[2][NBN];
#pragma unroll
  for (int i = 0; i < 2; i++)
#pragma unroll
    for (int j = 0; j < NBN; j++) acc[i][j] = (f32x4){0.f,0.f,0.f,0.f};

  const int r0 = m0 + lr;
#pragma unroll
  for (int ks = 0; ks < K/32; ks++){
    const int k0 = ks*32 + lq*8;
    bfrag a0 = {0,0,0,0,0,0,0,0}, a1 = {0,0,0,0,0,0,0,0};
    if (r0 < M)      a0 = *(const bfrag*)&Ac[(size_t)r0*K + k0];
    if (r0 + 16 < M) a1 = *(const bfrag*)&Ac[(size_t)(r0+16)*K + k0];
#pragma unroll
    for (int nb = 0; nb < NBN; nb++){
      bfrag bv = *(const bfrag*)&wlds[(nb*16 + lr)*KP + k0];
      acc[0][nb] = __builtin_amdgcn_mfma_f32_16x16x32_bf16(a0, bv, acc[0][nb], 0, 0, 0);
      acc[1][nb] = __builtin_amdgcn_mfma_f32_16x16x32_bf16(a1, bv, acc[1][nb], 0, 0, 0);
    }
  }

  float bv[NBN];
#pragma unroll
  for (int nb = 0; nb < NBN; nb++)
    bv[nb] = bias ? bias[wsel*bStr + nb*16 + lr] : 0.f;

#pragma unroll
  for (int mb = 0; mb < 2; mb++){
    __syncthreads();
#pragma unroll
    for (int nb = 0; nb < NBN; nb++){
      const int col = nb*16 + lr;
#pragma unroll
      for (int r = 0; r < 4; r++){
        float v = silu_f(acc[mb][nb][r] + bv[nb]);
        elds[(wave*16 + lq*4 + r)*PITCH + col] = v;
      }
    }
    __syncthreads();
    constexpr int CHUNKS = 64*N/4;
    for (int q = tid; q < CHUNKS; q += 256){
      int lrow = q / (N/4);
      int col0 = (q - lrow*(N/4))*4;
      int w = lrow >> 4, rr = lrow & 15;
      int grow = blockIdx.x*128 + w*32 + mb*16 + rr;
      if (grow >= M) continue;
      float4 v = *(float4*)&elds[lrow*PITCH + col0];
      size_t oi = (size_t)grow*N + col0;
      float o0 = v.x, o1 = v.y, o2 = v.z, o3 = v.w;
      if (MODE == 0){
        ushort4 av = *(const ushort4*)&auxc[oi];
        o0 *= b2f(av.x); o1 *= b2f(av.y); o2 *= b2f(av.z); o3 *= b2f(av.w);
      } else if (auxc){
        ushort4 av = *(const ushort4*)&auxc[oi];
        o0 += b2f(av.x); o1 += b2f(av.y); o2 += b2f(av.z); o3 += b2f(av.w);
      }
      ushort4 ov; ov.x = f2b(o0); ov.y = f2b(o1); ov.z = f2b(o2); ov.w = f2b(o3);
      *(ushort4*)&outc[oi] = ov;
    }
  }
}

// ================== register-resident fused chain ==================
// grid (ceil(E/128), 7), 256 threads = 4 waves x 32 rows. NO LDS, NO barriers.
// Swapped-operand 32x32x16 MFMA: A = weight frags (frag-major arena, coalesced
// 1KB global loads, L1/L2-resident), B = tile frags held in registers.
// Acc layout (m74/m101): lane holds col m = lane&31, row o = (reg&3)+8*(reg>>2)+4*(lane>>5).
// Repack acc->next B-frag is lane-local cvt_pk + a lane^32 exchange (shfl_xor).
// Residuals (t1/h/h2) live as packed-bf16 pairs in acc-reg order.
__global__ void __launch_bounds__(256, 2) k_chain(
    const u16* __restrict__ XB, const u16* __restrict__ AGGB,
    const u16* __restrict__ WTb,
    const float* __restrict__ bji, const float* __restrict__ bbs1,
    const float* __restrict__ bbs2, const float* __restrict__ blin,
    const float* __restrict__ bas1, const float* __restrict__ bas2,
    u16* __restrict__ OUT, int E)
{
  const int tid = threadIdx.x;
  const int wave = tid >> 6, l = tid & 63;
  const int hi = l >> 5;
  const int sl = blockIdx.y;
  const int b  = sl < 5 ? sl : 5;
  const size_t EH = (size_t)E*128, EI = (size_t)E*64;
  const int row = blockIdx.x*128 + wave*32 + (l & 31);
  const bool rok = row < E;
  const size_t rb = (size_t)(rok ? row : 0);    // clamp OOB rows to row 0 (never stored)

  const f32x16 Z = {0,0,0,0,0,0,0,0,0,0,0,0,0,0,0,0};
  f32x16 acc[4];      // acc[nb]: 32 features x 32 rows quadrant
  u32x4  fr[8];       // tile B-frags: fr[ks] = T[m][ks*16 + hi*8 + j]
  uint32_t pkv[4][8]; // packed bf16 pairs of current stage output (acc-reg order)
  uint32_t res[4][8]; // saved residual (t1 / h / h2 by phase)

  auto gemm128 = [&](const u16* __restrict__ Wf){
#pragma unroll
    for (int nb = 0; nb < 4; nb++) acc[nb] = Z;
#pragma unroll
    for (int ks = 0; ks < 8; ks++)
#pragma unroll
      for (int nb = 0; nb < 4; nb++){
        bfrag w = *(const bfrag*)&Wf[(size_t)(((nb*8 + ks)*64 + l)*8)];
        acc[nb] = __builtin_amdgcn_mfma_f32_32x32x16_bf16(
            w, __builtin_bit_cast(bfrag, fr[ks]), acc[nb], 0, 0, 0);
      }
  };

  // acc/pkv -> fr for next stage. Target lane (hi,m) frag[ks] needs features
  // o = ks*16 + hi*8 + j; sources are pkv[nb=ks>>1][g0..g0+3] with the upper
  // half coming from the lane^32 partner.
  auto repack = [&]{
#pragma unroll
    for (int ks = 0; ks < 8; ks++){
      const int nb = ks >> 1, g0 = (ks & 1)*4;
      uint32_t pA0 = pkv[nb][g0+0], pA1 = pkv[nb][g0+1];
      uint32_t pB0 = pkv[nb][g0+2], pB1 = pkv[nb][g0+3];
      uint32_t cA0 = __shfl_xor(pA0, 32);
      uint32_t cA1 = __shfl_xor(pA1, 32);
      uint32_t cB0 = __shfl_xor(pB0, 32);
      uint32_t cB1 = __shfl_xor(pB1, 32);
      u32x4 f;
      f.x = hi ? cB0 : pA0;   // j 0-1
      f.y = hi ? cB1 : pA1;   // j 2-3
      f.z = hi ? pB0 : cA0;   // j 4-5
      f.w = hi ? pB1 : cA1;   // j 6-7
      fr[ks] = f;
    }
  };

  // epilogue: mode 0 = silu(a+b); 1 = silu(a+b)+res, res=pkv; 2 = silu(a+b)+x, res=pkv
  auto epi = [&](const float* __restrict__ bp, int mode){
#pragma unroll
    for (int nb = 0; nb < 4; nb++){
      float4 bd0 = *(const float4*)&bp[nb*32 +  0 + 4*hi];
      float4 bd1 = *(const float4*)&bp[nb*32 +  8 + 4*hi];
      float4 bd2 = *(const float4*)&bp[nb*32 + 16 + 4*hi];
      float4 bd3 = *(const float4*)&bp[nb*32 + 24 + 4*hi];
      uint2 xv0, xv1, xv2, xv3;
      if (mode == 2){
        xv0 = *(const uint2*)&XB[rb*128 + nb*32 +  0 + 4*hi];
        xv1 = *(const uint2*)&XB[rb*128 + nb*32 +  8 + 4*hi];
        xv2 = *(const uint2*)&XB[rb*128 + nb*32 + 16 + 4*hi];
        xv3 = *(const uint2*)&XB[rb*128 + nb*32 + 24 + 4*hi];
      }
#pragma unroll
      for (int g = 0; g < 8; g++){
        const int d = g >> 1, s = g & 1;
        float4 bd = d==0 ? bd0 : d==1 ? bd1 : d==2 ? bd2 : bd3;
        float ba0 = s ? bd.z : bd.x;
        float ba1 = s ? bd.w : bd.y;
        float v0 = silu_f(acc[nb][2*g]   + ba0);
        float v1 = silu_f(acc[nb][2*g+1] + ba1);
        if (mode == 1){ v0 += lo16(res[nb][g]); v1 += hi16(res[nb][g]); }
        if (mode == 2){
          uint2 xd2 = d==0 ? xv0 : d==1 ? xv1 : d==2 ? xv2 : xv3;
          uint32_t xd = s ? xd2.y : xd2.x;
          v0 += lo16(xd); v1 += hi16(xd);
        }
        pkv[nb][g] = cvtpk(v0, v1);
      }
      if (mode != 0){
#pragma unroll
        for (int g = 0; g < 8; g++) res[nb][g] = pkv[nb][g];
      }
    }
  };

  // ---- S1: t1 = silu(agg_sl @ W_up)  [K=64, no bias] -> res ----
  {
#pragma unroll
    for (int ks = 0; ks < 4; ks++)
      fr[ks] = *(const u32x4*)&AGGB[(size_t)sl*EI + rb*64 + ks*16 + hi*8];
#pragma unroll
    for (int nb = 0; nb < 4; nb++) acc[nb] = Z;
    const u16* Wf = WTb + OFF_UP + b*8192;
#pragma unroll
    for (int ks = 0; ks < 4; ks++)
#pragma unroll
      for (int nb = 0; nb < 4; nb++){
        bfrag w = *(const bfrag*)&Wf[(size_t)(((nb*4 + ks)*64 + l)*8)];
        acc[nb] = __builtin_amdgcn_mfma_f32_32x32x16_bf16(
            w, __builtin_bit_cast(bfrag, fr[ks]), acc[nb], 0, 0, 0);
      }
#pragma unroll
    for (int nb = 0; nb < 4; nb++)
#pragma unroll
      for (int g = 0; g < 8; g++)
        res[nb][g] = cvtpk(silu_f(acc[nb][2*g]), silu_f(acc[nb][2*g+1]));
  }

  // ---- S2: h = silu(x @ W_ji + bji) + t1 ----
#pragma unroll
  for (int ks = 0; ks < 8; ks++)
    fr[ks] = *(const u32x4*)&XB[rb*128 + ks*16 + hi*8];
  gemm128(WTb + OFF_JI + b*16384);
  epi(bji + b*128, 1);
  repack();

  // ---- S3: t = silu(h @ W_bs1 + bbs1) ----
  gemm128(WTb + OFF_BS1 + b*16384);
  epi(bbs1 + b*128, 0);
  repack();

  // ---- S4: h = h + silu(t @ W_bs2 + bbs2) ----
  gemm128(WTb + OFF_BS2 + b*16384);
  epi(bbs2 + b*128, 1);
  repack();

  // ---- S5: h2 = silu(h @ W_lin + blin) + x ----
  gemm128(WTb + OFF_LIN + b*16384);
  epi(blin + b*128, 2);
  repack();

  // ---- S6: t2 = silu(h2 @ W_as1 + bas1) ----
  gemm128(WTb + OFF_AS1 + b*16384);
  epi(bas1 + b*128, 0);
  repack();

  // ---- S7: out = h2 + silu(t2 @ W_as2 + bas2) ----
  gemm128(WTb + OFF_AS2 + b*16384);
  epi(bas2 + b*128, 1);
  if (rok){
    const size_t ob = (size_t)sl*EH + (size_t)row*128;
#pragma unroll
    for (int nb = 0; nb < 4; nb++)
#pragma unroll
      for (int d = 0; d < 4; d++){
        uint2 o; o.x = pkv[nb][2*d]; o.y = pkv[nb][2*d+1];
        *(uint2*)&OUT[ob + nb*32 + d*8 + 4*hi] = o;
      }
  }
}

extern "C" void kernel_launch(void* const* d_in, const int* in_sizes, int n_in,
                              void* d_out, int out_size, void* d_ws, size_t ws_size,
                              hipStream_t stream)
{
  const float* x     = (const float*)d_in[0];
  const float* rbf   = (const float*)d_in[1];
  const float* sbf   = (const float*)d_in[2];
  const int*   ikj   = (const int*)d_in[3];
  const int*   iji   = (const int*)d_in[4];
  const int*   bt    = (const int*)d_in[5];
  const float* alphaP= (const float*)d_in[6];
  const float* Wrbf1 = (const float*)d_in[8];
  const float* Wrbf2 = (const float*)d_in[9];
  const float* Wsbf1 = (const float*)d_in[10];
  const float* Wsbf2 = (const float*)d_in[11];
  const float* Wkj   = (const float*)d_in[12];
  const float* bkj   = (const float*)d_in[13];
  const float* Wji   = (const float*)d_in[14];
  const float* bji   = (const float*)d_in[15];
  const float* Wdown = (const float*)d_in[16];
  const float* Wup   = (const float*)d_in[17];
  const float* Wbs1  = (const float*)d_in[18];
  const float* bbs1  = (const float*)d_in[19];
  const float* Wbs2  = (const float*)d_in[20];
  const float* bbs2  = (const float*)d_in[21];
  const float* Wlin  = (const float*)d_in[22];
  const float* blin  = (const float*)d_in[23];
  const float* Was1  = (const float*)d_in[24];
  const float* bas1  = (const float*)d_in[25];
  const float* Was2  = (const float*)d_in[26];
  const float* bas2  = (const float*)d_in[27];

  const int E = in_sizes[5];
  const int T = in_sizes[3];
  const int H = 128, I = 64;
  const size_t EH = (size_t)E*H, EI = (size_t)E*I;
  const int mt = (E + 127)/128;

  TW tw{Wkj, Wdown, Wji, Wup, Wbs1, Wbs2, Wlin, Was1, Was2, (u16*)0};

  char* ws = (char*)d_ws;
  size_t off = 0;
  auto arena = [&](size_t bytes)->size_t{
    size_t o = off; off += (bytes + 255) & ~(size_t)255; return o;
  };
  size_t oWT   = arena((size_t)WT_TOTAL*2);   // 1.33 MB
  size_t oXB   = arena(EH*2);                 // 25.6 MB
  size_t oXKJ  = arena(EI*2);                 // 12.8 MB
  size_t oAGGB = arena(7*EI*2);               // 89.6 MB
  size_t oBUF  = arena(2*(4*EH*2));           // 204.8 MB
  // pre-chain aliases inside BUF:
  //   AGG  fp32 6*EI*4 at BUF+0          (dead after k_cvt)
  //   S1   fp32 T*8*4  at BUF+153.6MB    (dead after k_triplet)
  //   RBF2 bf16 EH*2   at BUF+0          (dead after KJ)
  //   TMP  bf16 EH*2   at BUF+172.8MB    (dead after DOWN)
  // chain: OUT bf16 7*EH*2 = 179.2 MB at BUF+0
  if (off > ws_size) return;  // proven to fit (334 MB) — fail loudly otherwise

  u16*   WTb  = (u16*)(ws + oWT);
  u16*   XB   = (u16*)(ws + oXB);
  u16*   XKJ  = (u16*)(ws + oXKJ);
  u16*   AGGB = (u16*)(ws + oAGGB);
  char*  BUF  = ws + oBUF;
  u16*   OUT  = (u16*)BUF;
  float* AGG  = (float*)BUF;
  float* S1   = (float*)(BUF + 6*EI*4);
  u16*   RBF2 = (u16*)BUF;
  u16*   TMP  = (u16*)(BUF + 6*EI*4 + (size_t)T*8*4);

  tw.dst = WTb;
  hipLaunchKernelGGL(k_transpose, dim3(64, 44, 1), dim3(256, 1, 1), 0, stream, tw);
  k_f2b<<<dim3((int)((EH + 255)/256)), dim3(256), 0, stream>>>(x, XB, (int)EH);
  k_rbf<<<dim3((int)((EH + 255)/256)), dim3(256), 0, stream>>>(rbf, Wrbf1, Wrbf2, RBF2, E);
  // t = silu(x@W_kj+b)*rbf2 -> TMP
  k_gemmb<0,128,128><<<dim3(mt,1), dim3(256), 0, stream>>>(XB,0, WTb+OFF_KJ,0, bkj,0, RBF2,0, TMP,0, 0, E);
  // x_kj = silu(t@W_down) -> XKJ
  k_gemmb<1,64,128><<<dim3(mt,1), dim3(256), 0, stream>>>(TMP,0, WTb+OFF_DOWN,0, (const float*)0,0, (const u16*)0,0, XKJ,0, 0, E);
  k_s1<<<dim3((T + 255)/256), dim3(256), 0, stream>>>(sbf, Wsbf1, S1, T);
  hipMemsetAsync(BUF, 0, 6*EI*4, stream);
  k_triplet<<<dim3((int)(((size_t)T*64 + 255)/256)), dim3(256), 0, stream>>>(ikj, iji, bt, S1, Wsbf2, XKJ, AGG, T, E);
  k_cvt<<<dim3((int)((EI + 255)/256)), dim3(256), 0, stream>>>(AGG, AGGB, (int)EI);

  // register-resident chain: one dispatch, all 7 slices x 7 GEMMs, no LDS/barriers
  k_chain<<<dim3(mt, 7), dim3(256), 0, stream>>>(XB, AGGB, WTb,
      bji, bbs1, bbs2, blin, bas1, bas2, OUT, E);
  // fold all 7 slices into d_out (slice 6 = generic -> alpha)
  k_red<<<dim3((int)((EH/4 + 255)/256)), dim3(256), 0, stream>>>(OUT, alphaP, (float*)d_out, EH, 7, 1, 0);
  (void)n_in; (void)out_size;
}

// Round 3
// 1068.069 us; speedup vs baseline: 1.2858x; 1.2858x over previous
//
#include <hip/hip_runtime.h>
#include <stdint.h>

typedef unsigned short u16;
typedef __attribute__((ext_vector_type(8))) short bfrag;   // 8 bf16 = 4 VGPR MFMA operand
typedef __attribute__((ext_vector_type(4))) float f32x4;
typedef __attribute__((ext_vector_type(16))) float f32x16; // 32x32 MFMA accumulator
typedef __attribute__((ext_vector_type(4))) unsigned int u32x4;

#define DEVI __device__ __forceinline__

DEVI float b2f(u16 u){ return __uint_as_float(((uint32_t)u) << 16); }
DEVI u16 f2b(float f){
  uint32_t x = __float_as_uint(f);
  uint32_t r = (x + 0x7fffu + ((x >> 16) & 1u)) >> 16;   // RNE
  return (u16)r;
}
DEVI float silu_f(float v){ return v / (1.0f + __expf(-v)); }
DEVI float lo16(uint32_t w){ return b2f((u16)(w & 0xffffu)); }
DEVI float hi16(uint32_t w){ return b2f((u16)(w >> 16)); }
DEVI uint32_t cvtpk(float lo, float hi){
  uint32_t r;
  asm("v_cvt_pk_bf16_f32 %0, %1, %2" : "=v"(r) : "v"(lo), "v"(hi));
  return r;
}

// ---- weight arena element offsets (bf16 elements) ----
// KJ/DOWN: transposed [N][K] row-major (for k_gemmb).
// Chain weights (JI/UP/BS1/BS2/LIN/AS1/AS2): FRAGMENT-MAJOR for 32x32x16 MFMA:
//   elem idx = ((nb*KS + ks)*64 + lane)*8 + j  holds W[o][k],
//   o = nb*32 + (lane&31), k = ks*16 + (lane>>5)*8 + j   (KS = K/16)
// Frag-major is LINEAR in memory -> exactly global_load_lds's wave layout.
#define OFF_KJ   0
#define OFF_DOWN 16384
#define OFF_JI   24576
#define OFF_UP   122880
#define OFF_BS1  172032
#define OFF_BS2  270336
#define OFF_LIN  368640
#define OFF_AS1  466944
#define OFF_AS2  565248
#define WT_TOTAL 663552

struct TW {
  const float *kj, *down, *ji, *up, *bs1, *bs2, *lin, *as1, *as2;
  u16* dst;
};

// Transpose+convert all weight matrices once. mode 0: [K,N]->[N,K];
// mode 1: frag-major K=128; mode 2: frag-major K=64.
__global__ void __launch_bounds__(256) k_transpose(TW p){
  int id = blockIdx.y;
  const float* src; int K, N, doff, mode;
  if      (id == 0) { src = p.kj;   K = 128; N = 128; doff = OFF_KJ;   mode = 0; }
  else if (id == 1) { src = p.down; K = 128; N = 64;  doff = OFF_DOWN; mode = 0; }
  else if (id < 8)  { int b = id - 2;  src = p.ji  + b*16384; K = 128; N = 128; doff = OFF_JI  + b*16384; mode = 1; }
  else if (id < 14) { int b = id - 8;  src = p.up  + b*8192;  K = 64;  N = 128; doff = OFF_UP  + b*8192;  mode = 2; }
  else if (id < 20) { int b = id - 14; src = p.bs1 + b*16384; K = 128; N = 128; doff = OFF_BS1 + b*16384; mode = 1; }
  else if (id < 26) { int b = id - 20; src = p.bs2 + b*16384; K = 128; N = 128; doff = OFF_BS2 + b*16384; mode = 1; }
  else if (id < 32) { int b = id - 26; src = p.lin + b*16384; K = 128; N = 128; doff = OFF_LIN + b*16384; mode = 1; }
  else if (id < 38) { int b = id - 32; src = p.as1 + b*16384; K = 128; N = 128; doff = OFF_AS1 + b*16384; mode = 1; }
  else              { int b = id - 38; src = p.as2 + b*16384; K = 128; N = 128; doff = OFF_AS2 + b*16384; mode = 1; }
  int idx = blockIdx.x*256 + threadIdx.x;
  if (idx >= K*N) return;
  float v;
  if (mode == 0){
    int n = idx / K, k = idx - n*K;
    v = src[k*N + n];
  } else if (mode == 1){
    int j = idx & 7, lv = (idx >> 3) & 63, ks = (idx >> 9) & 7, nb = idx >> 12;
    int o = nb*32 + (lv & 31), k = ks*16 + (lv >> 5)*8 + j;
    v = src[k*128 + o];
  } else {
    int j = idx & 7, lv = (idx >> 3) & 63, ks = (idx >> 9) & 3, nb = idx >> 11;
    int o = nb*32 + (lv & 31), k = ks*16 + (lv >> 5)*8 + j;
    v = src[k*128 + o];
  }
  p.dst[doff + idx] = f2b(v);
}

// elementwise fp32 -> bf16
__global__ void __launch_bounds__(256) k_f2b(
    const float* __restrict__ src, u16* __restrict__ dst, int n)
{
  int i = blockIdx.x*256 + threadIdx.x;
  if (i < n) dst[i] = f2b(src[i]);
}

// rbf2[e,h] = ((rbf @ W_rbf1) @ W_rbf2)[e,h]
__global__ void __launch_bounds__(256) k_rbf(
    const float* __restrict__ rbf, const float* __restrict__ W1,
    const float* __restrict__ W2, u16* __restrict__ out, int E)
{
  __shared__ float w1s[48];
  __shared__ float w2s[1024];
  for (int i = threadIdx.x; i < 48;   i += 256) w1s[i] = W1[i];
  for (int i = threadIdx.x; i < 1024; i += 256) w2s[i] = W2[i];
  __syncthreads();
  int idx = blockIdx.x*256 + threadIdx.x;
  if (idx >= E*128) return;
  int e = idx >> 7, h = idx & 127;
  float rv[6];
#pragma unroll
  for (int k = 0; k < 6; k++) rv[k] = rbf[e*6 + k];
  float o = 0.f;
#pragma unroll
  for (int j = 0; j < 8; j++){
    float m = 0.f;
#pragma unroll
    for (int k = 0; k < 6; k++) m += rv[k] * w1s[k*8 + j];
    o += m * w2s[j*128 + h];
  }
  out[idx] = f2b(o);
}

// s1[t,0:8] = (sbf @ W_sbf1)[t]
__global__ void __launch_bounds__(256) k_s1(
    const float* __restrict__ sbf, const float* __restrict__ W1,
    float* __restrict__ s1, int T)
{
  __shared__ float w1s[336];
  for (int i = threadIdx.x; i < 336; i += 256) w1s[i] = W1[i];
  __syncthreads();
  int t = blockIdx.x*256 + threadIdx.x;
  if (t >= T) return;
  const float* row = sbf + (size_t)t*42;
  float a[8];
#pragma unroll
  for (int j = 0; j < 8; j++) a[j] = 0.f;
  for (int k = 0; k < 42; k++){
    float sv = row[k];
#pragma unroll
    for (int j = 0; j < 8; j++) a[j] += sv * w1s[k*8 + j];
  }
#pragma unroll
  for (int j = 0; j < 8; j++) s1[(size_t)t*8 + j] = a[j];
}

// one wave per triplet: sbf_e = s1 @ W_sbf2; v = x_kj[idx_kj]*sbf_e; scatter into agg[branch]
__global__ void __launch_bounds__(256) k_triplet(
    const int* __restrict__ idx_kj, const int* __restrict__ idx_ji,
    const int* __restrict__ bt, const float* __restrict__ s1,
    const float* __restrict__ Wsbf2, const u16* __restrict__ xkj,
    float* __restrict__ agg, int T, int E)
{
  int g = blockIdx.x*256 + threadIdx.x;
  int t = g >> 6, lane = g & 63;
  if (t >= T) return;
  int kj = idx_kj[t], ji = idx_ji[t];
  int b = bt[kj] + 1;
  b = b < 0 ? 0 : (b > 5 ? 5 : b);
  float se = 0.f;
#pragma unroll
  for (int j = 0; j < 8; j++) se += s1[(size_t)t*8 + j] * Wsbf2[j*64 + lane];
  float v = b2f(xkj[(size_t)kj*64 + lane]) * se;
  unsafeAtomicAdd(&agg[((size_t)b*E + ji)*64 + lane], v);
}

// agg fp32 -> aggb bf16 slots 0..5, slot 6 = sum (== agg_gen)
__global__ void __launch_bounds__(256) k_cvt(
    const float* __restrict__ agg, u16* __restrict__ aggb, int EI)
{
  int idx = blockIdx.x*256 + threadIdx.x;
  if (idx >= EI) return;
  float s = 0.f;
#pragma unroll
  for (int b = 0; b < 6; b++){
    float v = agg[(size_t)b*EI + idx];
    s += v;
    aggb[(size_t)b*EI + idx] = f2b(v);
  }
  aggb[(size_t)6*EI + idx] = f2b(s);
}

// reduce nsl slices of S into out (fp32)
__global__ void __launch_bounds__(256) k_red(
    const u16* __restrict__ S, const float* __restrict__ alphaP,
    float* __restrict__ out, size_t EH, int nsl, int genLast, int accum)
{
  size_t base = ((size_t)blockIdx.x*256 + threadIdx.x)*4;
  if (base >= EH) return;
  float al = alphaP[0];
  float s0=0,s1=0,s2=0,s3=0;
  for (int c = 0; c < nsl; c++){
    float sc = (genLast && c == nsl-1) ? al : (1.f - al);
    ushort4 v = *(const ushort4*)&S[(size_t)c*EH + base];
    s0 += sc*b2f(v.x); s1 += sc*b2f(v.y); s2 += sc*b2f(v.z); s3 += sc*b2f(v.w);
  }
  float4 o;
  if (accum){
    float4 p = *(const float4*)&out[base];
    o.x = p.x + s0; o.y = p.y + s1; o.z = p.z + s2; o.w = p.w + s3;
  } else {
    o.x = s0; o.y = s1; o.z = s2; o.w = s3;
  }
  *(float4*)&out[base] = o;
}

// ================== batched fused-epilogue MFMA GEMM (pre-chain) ==================
template<int MODE, int N, int K>
__global__ void __launch_bounds__(256) k_gemmb(
    const u16* __restrict__ A, size_t aStr,
    const u16* __restrict__ WTp, int wStr,
    const float* __restrict__ bias, int bStr,
    const u16* __restrict__ aux, size_t xStr,
    u16* __restrict__ out, size_t oStr,
    int cBase, int M)
{
  constexpr int KP = K + 8;
  constexpr int PITCH = N + 4;
  constexpr size_t SW = (size_t)KP*N*2;
  constexpr size_t SE = (size_t)64*PITCH*4;
  constexpr size_t SMEM = SW > SE ? SW : SE;
  __shared__ __attribute__((aligned(16))) char smem[SMEM];
  u16*   wlds = (u16*)smem;
  float* elds = (float*)smem;

  const int tid = threadIdx.x;
  const int sl = blockIdx.y;
  const int c = cBase + sl;
  const int wsel = c < 5 ? c : 5;
  const u16* __restrict__ Ac = A + (size_t)sl*aStr;
  const u16* __restrict__ Wc = WTp + (size_t)wsel*wStr;
  const u16* __restrict__ auxc = aux ? aux + (size_t)sl*xStr : (const u16*)0;
  u16* __restrict__ outc = out + (size_t)sl*oStr;

  constexpr int CH = (N*K)/8;
  for (int ch = tid; ch < CH; ch += 256){
    int n  = ch / (K/8);
    int kc = (ch - n*(K/8))*8;
    *(int4*)&wlds[n*KP + kc] = *(const int4*)&Wc[n*K + kc];
  }
  __syncthreads();

  const int wave = tid >> 6, lane = tid & 63;
  const int lr = lane & 15, lq = lane >> 4;
  const int m0 = blockIdx.x*128 + wave*32;
  constexpr int NBN = N/16;
  f32x4 acc[2][NBN];
#pragma unroll
  for (int i = 0; i < 2; i++)
#pragma unroll
    for (int j = 0; j < NBN; j++) acc[i][j] = (f32x4){0.f,0.f,0.f,0.f};

  const int r0 = m0 + lr;
#pragma unroll
  for (int ks = 0; ks < K/32; ks++){
    const int k0 = ks*32 + lq*8;
    bfrag a0 = {0,0,0,0,0,0,0,0}, a1 = {0,0,0,0,0,0,0,0};
    if (r0 < M)      a0 = *(const bfrag*)&Ac[(size_t)r0*K + k0];
    if (r0 + 16 < M) a1 = *(const bfrag*)&Ac[(size_t)(r0+16)*K + k0];
#pragma unroll
    for (int nb = 0; nb < NBN; nb++){
      bfrag bv = *(const bfrag*)&wlds[(nb*16 + lr)*KP + k0];
      acc[0][nb] = __builtin_amdgcn_mfma_f32_16x16x32_bf16(a0, bv, acc[0][nb], 0, 0, 0);
      acc[1][nb] = __builtin_amdgcn_mfma_f32_16x16x32_bf16(a1, bv, acc[1][nb], 0, 0, 0);
    }
  }

  float bv[NBN];
#pragma unroll
  for (int nb = 0; nb < NBN; nb++)
    bv[nb] = bias ? bias[wsel*bStr + nb*16 + lr] : 0.f;

#pragma unroll
  for (int mb = 0; mb < 2; mb++){
    __syncthreads();
#pragma unroll
    for (int nb = 0; nb < NBN; nb++){
      const int col = nb*16 + lr;
#pragma unroll
      for (int r = 0; r < 4; r++){
        float v = silu_f(acc[mb][nb][r] + bv[nb]);
        elds[(wave*16 + lq*4 + r)*PITCH + col] = v;
      }
    }
    __syncthreads();
    constexpr int CHUNKS = 64*N/4;
    for (int q = tid; q < CHUNKS; q += 256){
      int lrow = q / (N/4);
      int col0 = (q - lrow*(N/4))*4;
      int w = lrow >> 4, rr = lrow & 15;
      int grow = blockIdx.x*128 + w*32 + mb*16 + rr;
      if (grow >= M) continue;
      float4 v = *(float4*)&elds[lrow*PITCH + col0];
      size_t oi = (size_t)grow*N + col0;
      float o0 = v.x, o1 = v.y, o2 = v.z, o3 = v.w;
      if (MODE == 0){
        ushort4 av = *(const ushort4*)&auxc[oi];
        o0 *= b2f(av.x); o1 *= b2f(av.y); o2 *= b2f(av.z); o3 *= b2f(av.w);
      } else if (auxc){
        ushort4 av = *(const ushort4*)&auxc[oi];
        o0 += b2f(av.x); o1 += b2f(av.y); o2 += b2f(av.z); o3 += b2f(av.w);
      }
      ushort4 ov; ov.x = f2b(o0); ov.y = f2b(o1); ov.z = f2b(o2); ov.w = f2b(o3);
      *(ushort4*)&outc[oi] = ov;
    }
  }
}

// ================== register-tile chain, LDS-staged weights ==================
// grid (ceil(E/128), 7), 256 threads = 4 waves x 32 rows.
// Tile stays in registers (R2 repack, verified); weights are staged per stage
// into a 2x32KB LDS double buffer via global_load_lds (frag-major = linear =
// exactly the wave-uniform-base + lane*16 layout the instruction requires).
// Stage s prefetches stage s+1's weights; the compiler's vmcnt(0) drain at the
// per-stage __syncthreads() guarantees they have landed. Weight ds_read_b128s
// are one base + immediate offsets, conflict-free by construction.
__global__ void __launch_bounds__(256, 2) k_chain(
    const u16* __restrict__ XB, const u16* __restrict__ AGGB,
    const u16* __restrict__ WTb,
    const float* __restrict__ bji, const float* __restrict__ bbs1,
    const float* __restrict__ bbs2, const float* __restrict__ blin,
    const float* __restrict__ bas1, const float* __restrict__ bas2,
    u16* __restrict__ OUT, int E)
{
  __shared__ __attribute__((aligned(16))) u16 wbuf[2][16384];   // 64 KB

  const int tid = threadIdx.x;
  const int wave = tid >> 6, l = tid & 63;
  const int hi = l >> 5;
  const int sl = blockIdx.y;
  const int b  = sl < 5 ? sl : 5;
  const size_t EH = (size_t)E*128, EI = (size_t)E*64;
  const int row = blockIdx.x*128 + wave*32 + (l & 31);
  const bool rok = row < E;
  const size_t rb = (size_t)(rok ? row : 0);    // clamp OOB rows to row 0 (never stored)

  const f32x16 Z = {0,0,0,0,0,0,0,0,0,0,0,0,0,0,0,0};
  f32x16 acc[4];      // acc[nb]: 32 features x 32 rows quadrant
  u32x4  fr[8];       // tile B-frags: fr[ks] = T[m][ks*16 + hi*8 + j]
  uint32_t pkv[4][8]; // packed bf16 pairs of current stage output (acc-reg order)
  uint32_t res[4][8]; // saved residual (t1 / h / h2 by phase)

  // stage weights (nch x 1KB chunks) into wbuf[bufi] via async global->LDS.
  // LDS dest is wave-uniform base; HW scatters lane i at base + i*16.
  auto stageW = [&](const u16* Wg, int nch, int bufi){
    for (int i = wave; i < nch; i += 4){
      const u16* g = Wg + i*512 + l*8;
      __builtin_amdgcn_global_load_lds(
          (const __attribute__((address_space(1))) void*)g,
          (__attribute__((address_space(3))) void*)&wbuf[bufi][i*512],
          16, 0, 0);
    }
  };

  auto gemm128L = [&](int bufi){
#pragma unroll
    for (int nb = 0; nb < 4; nb++) acc[nb] = Z;
#pragma unroll
    for (int ks = 0; ks < 8; ks++)
#pragma unroll
      for (int nb = 0; nb < 4; nb++){
        bfrag w = *(const bfrag*)&wbuf[bufi][((nb*8 + ks)*64 + l)*8];
        acc[nb] = __builtin_amdgcn_mfma_f32_32x32x16_bf16(
            w, __builtin_bit_cast(bfrag, fr[ks]), acc[nb], 0, 0, 0);
      }
  };

  // acc/pkv -> fr for next stage (lane-local cvt_pk pairs + lane^32 exchange).
  auto repack = [&]{
#pragma unroll
    for (int ks = 0; ks < 8; ks++){
      const int nb = ks >> 1, g0 = (ks & 1)*4;
      uint32_t pA0 = pkv[nb][g0+0], pA1 = pkv[nb][g0+1];
      uint32_t pB0 = pkv[nb][g0+2], pB1 = pkv[nb][g0+3];
      uint32_t cA0 = __shfl_xor(pA0, 32);
      uint32_t cA1 = __shfl_xor(pA1, 32);
      uint32_t cB0 = __shfl_xor(pB0, 32);
      uint32_t cB1 = __shfl_xor(pB1, 32);
      u32x4 f;
      f.x = hi ? cB0 : pA0;   // j 0-1
      f.y = hi ? cB1 : pA1;   // j 2-3
      f.z = hi ? pB0 : cA0;   // j 4-5
      f.w = hi ? pB1 : cA1;   // j 6-7
      fr[ks] = f;
    }
  };

  // epilogue: mode 0 = silu(a+b); 1 = silu(a+b)+res, res=pkv; 2 = silu(a+b)+x, res=pkv
  auto epi = [&](const float* __restrict__ bp, int mode){
#pragma unroll
    for (int nb = 0; nb < 4; nb++){
      float4 bd0 = *(const float4*)&bp[nb*32 +  0 + 4*hi];
      float4 bd1 = *(const float4*)&bp[nb*32 +  8 + 4*hi];
      float4 bd2 = *(const float4*)&bp[nb*32 + 16 + 4*hi];
      float4 bd3 = *(const float4*)&bp[nb*32 + 24 + 4*hi];
      uint2 xv0, xv1, xv2, xv3;
      if (mode == 2){
        xv0 = *(const uint2*)&XB[rb*128 + nb*32 +  0 + 4*hi];
        xv1 = *(const uint2*)&XB[rb*128 + nb*32 +  8 + 4*hi];
        xv2 = *(const uint2*)&XB[rb*128 + nb*32 + 16 + 4*hi];
        xv3 = *(const uint2*)&XB[rb*128 + nb*32 + 24 + 4*hi];
      }
#pragma unroll
      for (int g = 0; g < 8; g++){
        const int d = g >> 1, s = g & 1;
        float4 bd = d==0 ? bd0 : d==1 ? bd1 : d==2 ? bd2 : bd3;
        float ba0 = s ? bd.z : bd.x;
        float ba1 = s ? bd.w : bd.y;
        float v0 = silu_f(acc[nb][2*g]   + ba0);
        float v1 = silu_f(acc[nb][2*g+1] + ba1);
        if (mode == 1){ v0 += lo16(res[nb][g]); v1 += hi16(res[nb][g]); }
        if (mode == 2){
          uint2 xd2 = d==0 ? xv0 : d==1 ? xv1 : d==2 ? xv2 : xv3;
          uint32_t xd = s ? xd2.y : xd2.x;
          v0 += lo16(xd); v1 += hi16(xd);
        }
        pkv[nb][g] = cvtpk(v0, v1);
      }
      if (mode != 0){
#pragma unroll
        for (int g = 0; g < 8; g++) res[nb][g] = pkv[nb][g];
      }
    }
  };

  // ---- prologue: W_up (16KB) -> buf0 ----
  stageW(WTb + OFF_UP + b*8192, 16, 0);
  __syncthreads();                         // vmcnt drain: W_up ready

  // ---- S1: t1 = silu(agg_sl @ W_up)  [K=64, no bias] -> res ----
  {
#pragma unroll
    for (int ks = 0; ks < 4; ks++)
      fr[ks] = *(const u32x4*)&AGGB[(size_t)sl*EI + rb*64 + ks*16 + hi*8];
    stageW(WTb + OFF_JI + b*16384, 32, 1); // prefetch W_ji
#pragma unroll
    for (int nb = 0; nb < 4; nb++) acc[nb] = Z;
#pragma unroll
    for (int ks = 0; ks < 4; ks++)
#pragma unroll
      for (int nb = 0; nb < 4; nb++){
        bfrag w = *(const bfrag*)&wbuf[0][((nb*4 + ks)*64 + l)*8];
        acc[nb] = __builtin_amdgcn_mfma_f32_32x32x16_bf16(
            w, __builtin_bit_cast(bfrag, fr[ks]), acc[nb], 0, 0, 0);
      }
#pragma unroll
    for (int nb = 0; nb < 4; nb++)
#pragma unroll
      for (int g = 0; g < 8; g++)
        res[nb][g] = cvtpk(silu_f(acc[nb][2*g]), silu_f(acc[nb][2*g+1]));
  }
  __syncthreads();                         // W_ji ready; all waves done with buf0

  // ---- S2: h = silu(x @ W_ji + bji) + t1 ----
#pragma unroll
  for (int ks = 0; ks < 8; ks++)
    fr[ks] = *(const u32x4*)&XB[rb*128 + ks*16 + hi*8];
  stageW(WTb + OFF_BS1 + b*16384, 32, 0);  // prefetch W_bs1
  gemm128L(1);
  epi(bji + b*128, 1);
  repack();
  __syncthreads();

  // ---- S3: t = silu(h @ W_bs1 + bbs1) ----
  stageW(WTb + OFF_BS2 + b*16384, 32, 1);
  gemm128L(0);
  epi(bbs1 + b*128, 0);
  repack();
  __syncthreads();

  // ---- S4: h = h + silu(t @ W_bs2 + bbs2) ----
  stageW(WTb + OFF_LIN + b*16384, 32, 0);
  gemm128L(1);
  epi(bbs2 + b*128, 1);
  repack();
  __syncthreads();

  // ---- S5: h2 = silu(h @ W_lin + blin) + x ----
  stageW(WTb + OFF_AS1 + b*16384, 32, 1);
  gemm128L(0);
  epi(blin + b*128, 2);
  repack();
  __syncthreads();

  // ---- S6: t2 = silu(h2 @ W_as1 + bas1) ----
  stageW(WTb + OFF_AS2 + b*16384, 32, 0);
  gemm128L(1);
  epi(bas1 + b*128, 0);
  repack();
  __syncthreads();

  // ---- S7: out = h2 + silu(t2 @ W_as2 + bas2) ----
  gemm128L(0);
  epi(bas2 + b*128, 1);
  if (rok){
    const size_t ob = (size_t)sl*EH + (size_t)row*128;
#pragma unroll
    for (int nb = 0; nb < 4; nb++)
#pragma unroll
      for (int d = 0; d < 4; d++){
        uint2 o; o.x = pkv[nb][2*d]; o.y = pkv[nb][2*d+1];
        *(uint2*)&OUT[ob + nb*32 + d*8 + 4*hi] = o;
      }
  }
}

extern "C" void kernel_launch(void* const* d_in, const int* in_sizes, int n_in,
                              void* d_out, int out_size, void* d_ws, size_t ws_size,
                              hipStream_t stream)
{
  const float* x     = (const float*)d_in[0];
  const float* rbf   = (const float*)d_in[1];
  const float* sbf   = (const float*)d_in[2];
  const int*   ikj   = (const int*)d_in[3];
  const int*   iji   = (const int*)d_in[4];
  const int*   bt    = (const int*)d_in[5];
  const float* alphaP= (const float*)d_in[6];
  const float* Wrbf1 = (const float*)d_in[8];
  const float* Wrbf2 = (const float*)d_in[9];
  const float* Wsbf1 = (const float*)d_in[10];
  const float* Wsbf2 = (const float*)d_in[11];
  const float* Wkj   = (const float*)d_in[12];
  const float* bkj   = (const float*)d_in[13];
  const float* Wji   = (const float*)d_in[14];
  const float* bji   = (const float*)d_in[15];
  const float* Wdown = (const float*)d_in[16];
  const float* Wup   = (const float*)d_in[17];
  const float* Wbs1  = (const float*)d_in[18];
  const float* bbs1  = (const float*)d_in[19];
  const float* Wbs2  = (const float*)d_in[20];
  const float* bbs2  = (const float*)d_in[21];
  const float* Wlin  = (const float*)d_in[22];
  const float* blin  = (const float*)d_in[23];
  const float* Was1  = (const float*)d_in[24];
  const float* bas1  = (const float*)d_in[25];
  const float* Was2  = (const float*)d_in[26];
  const float* bas2  = (const float*)d_in[27];

  const int E = in_sizes[5];
  const int T = in_sizes[3];
  const int H = 128, I = 64;
  const size_t EH = (size_t)E*H, EI = (size_t)E*I;
  const int mt = (E + 127)/128;

  TW tw{Wkj, Wdown, Wji, Wup, Wbs1, Wbs2, Wlin, Was1, Was2, (u16*)0};

  char* ws = (char*)d_ws;
  size_t off = 0;
  auto arena = [&](size_t bytes)->size_t{
    size_t o = off; off += (bytes + 255) & ~(size_t)255; return o;
  };
  size_t oWT   = arena((size_t)WT_TOTAL*2);   // 1.33 MB
  size_t oXB   = arena(EH*2);                 // 25.6 MB
  size_t oXKJ  = arena(EI*2);                 // 12.8 MB
  size_t oAGGB = arena(7*EI*2);               // 89.6 MB
  size_t oBUF  = arena(2*(4*EH*2));           // 204.8 MB
  // pre-chain aliases inside BUF:
  //   AGG  fp32 6*EI*4 at BUF+0          (dead after k_cvt)
  //   S1   fp32 T*8*4  at BUF+153.6MB    (dead after k_triplet)
  //   RBF2 bf16 EH*2   at BUF+0          (dead after KJ)
  //   TMP  bf16 EH*2   at BUF+172.8MB    (dead after DOWN)
  // chain: OUT bf16 7*EH*2 = 179.2 MB at BUF+0
  if (off > ws_size) return;

  u16*   WTb  = (u16*)(ws + oWT);
  u16*   XB   = (u16*)(ws + oXB);
  u16*   XKJ  = (u16*)(ws + oXKJ);
  u16*   AGGB = (u16*)(ws + oAGGB);
  char*  BUF  = ws + oBUF;
  u16*   OUT  = (u16*)BUF;
  float* AGG  = (float*)BUF;
  float* S1   = (float*)(BUF + 6*EI*4);
  u16*   RBF2 = (u16*)BUF;
  u16*   TMP  = (u16*)(BUF + 6*EI*4 + (size_t)T*8*4);

  tw.dst = WTb;
  hipLaunchKernelGGL(k_transpose, dim3(64, 44, 1), dim3(256, 1, 1), 0, stream, tw);
  k_f2b<<<dim3((int)((EH + 255)/256)), dim3(256), 0, stream>>>(x, XB, (int)EH);
  k_rbf<<<dim3((int)((EH + 255)/256)), dim3(256), 0, stream>>>(rbf, Wrbf1, Wrbf2, RBF2, E);
  // t = silu(x@W_kj+b)*rbf2 -> TMP
  k_gemmb<0,128,128><<<dim3(mt,1), dim3(256), 0, stream>>>(XB,0, WTb+OFF_KJ,0, bkj,0, RBF2,0, TMP,0, 0, E);
  // x_kj = silu(t@W_down) -> XKJ
  k_gemmb<1,64,128><<<dim3(mt,1), dim3(256), 0, stream>>>(TMP,0, WTb+OFF_DOWN,0, (const float*)0,0, (const u16*)0,0, XKJ,0, 0, E);
  k_s1<<<dim3((T + 255)/256), dim3(256), 0, stream>>>(sbf, Wsbf1, S1, T);
  hipMemsetAsync(BUF, 0, 6*EI*4, stream);
  k_triplet<<<dim3((int)(((size_t)T*64 + 255)/256)), dim3(256), 0, stream>>>(ikj, iji, bt, S1, Wsbf2, XKJ, AGG, T, E);
  k_cvt<<<dim3((int)((EI + 255)/256)), dim3(256), 0, stream>>>(AGG, AGGB, (int)EI);

  // register-tile chain with LDS-staged weights: one dispatch, 7 slices x 7 GEMMs
  k_chain<<<dim3(mt, 7), dim3(256), 0, stream>>>(XB, AGGB, WTb,
      bji, bbs1, bbs2, blin, bas1, bas2, OUT, E);
  // fold all 7 slices into d_out (slice 6 = generic -> alpha)
  k_red<<<dim3((int)((EH/4 + 255)/256)), dim3(256), 0, stream>>>(OUT, alphaP, (float*)d_out, EH, 7, 1, 0);
  (void)n_in; (void)out_size;
}

// Round 4
// 912.013 us; speedup vs baseline: 1.5058x; 1.1711x over previous
//
#include <hip/hip_runtime.h>
#include <stdint.h>

typedef unsigned short u16;
typedef __attribute__((ext_vector_type(8))) short bfrag;   // 8 bf16 = 4 VGPR MFMA operand
typedef __attribute__((ext_vector_type(4))) float f32x4;
typedef __attribute__((ext_vector_type(16))) float f32x16; // 32x32 MFMA accumulator
typedef __attribute__((ext_vector_type(4))) unsigned int u32x4;
typedef __attribute__((ext_vector_type(2))) unsigned int u32x2;

#define DEVI __device__ __forceinline__

DEVI float b2f(u16 u){ return __uint_as_float(((uint32_t)u) << 16); }
DEVI u16 f2b(float f){
  uint32_t x = __float_as_uint(f);
  uint32_t r = (x + 0x7fffu + ((x >> 16) & 1u)) >> 16;   // RNE
  return (u16)r;
}
// fast silu: v_rcp_f32 (1ulp) instead of IEEE division (10+ instr without fast-math).
// All consumers round to bf16, so the rcp error is far below output ulp.
DEVI float silu_f(float v){ return v * __builtin_amdgcn_rcpf(1.0f + __expf(-v)); }
DEVI float lo16(uint32_t w){ return b2f((u16)(w & 0xffffu)); }
DEVI float hi16(uint32_t w){ return b2f((u16)(w >> 16)); }
DEVI uint32_t cvtpk(float lo, float hi){
  uint32_t r;
  asm("v_cvt_pk_bf16_f32 %0, %1, %2" : "=v"(r) : "v"(lo), "v"(hi));
  return r;
}

// ---- weight arena element offsets (bf16 elements) ----
// KJ/DOWN: transposed [N][K] row-major (for k_gemmb).
// Chain weights (JI/UP/BS1/BS2/LIN/AS1/AS2): FRAGMENT-MAJOR for 32x32x16 MFMA:
//   elem idx = ((nb*KS + ks)*64 + lane)*8 + j  holds W[o][k],
//   o = nb*32 + (lane&31), k = ks*16 + (lane>>5)*8 + j   (KS = K/16)
// Frag-major is LINEAR in memory -> exactly global_load_lds's wave layout.
#define OFF_KJ   0
#define OFF_DOWN 16384
#define OFF_JI   24576
#define OFF_UP   122880
#define OFF_BS1  172032
#define OFF_BS2  270336
#define OFF_LIN  368640
#define OFF_AS1  466944
#define OFF_AS2  565248
#define WT_TOTAL 663552

struct TW {
  const float *kj, *down, *ji, *up, *bs1, *bs2, *lin, *as1, *as2;
  u16* dst;
};

// Transpose+convert all weight matrices once. mode 0: [K,N]->[N,K];
// mode 1: frag-major K=128; mode 2: frag-major K=64.
__global__ void __launch_bounds__(256) k_transpose(TW p){
  int id = blockIdx.y;
  const float* src; int K, N, doff, mode;
  if      (id == 0) { src = p.kj;   K = 128; N = 128; doff = OFF_KJ;   mode = 0; }
  else if (id == 1) { src = p.down; K = 128; N = 64;  doff = OFF_DOWN; mode = 0; }
  else if (id < 8)  { int b = id - 2;  src = p.ji  + b*16384; K = 128; N = 128; doff = OFF_JI  + b*16384; mode = 1; }
  else if (id < 14) { int b = id - 8;  src = p.up  + b*8192;  K = 64;  N = 128; doff = OFF_UP  + b*8192;  mode = 2; }
  else if (id < 20) { int b = id - 14; src = p.bs1 + b*16384; K = 128; N = 128; doff = OFF_BS1 + b*16384; mode = 1; }
  else if (id < 26) { int b = id - 20; src = p.bs2 + b*16384; K = 128; N = 128; doff = OFF_BS2 + b*16384; mode = 1; }
  else if (id < 32) { int b = id - 26; src = p.lin + b*16384; K = 128; N = 128; doff = OFF_LIN + b*16384; mode = 1; }
  else if (id < 38) { int b = id - 32; src = p.as1 + b*16384; K = 128; N = 128; doff = OFF_AS1 + b*16384; mode = 1; }
  else              { int b = id - 38; src = p.as2 + b*16384; K = 128; N = 128; doff = OFF_AS2 + b*16384; mode = 1; }
  int idx = blockIdx.x*256 + threadIdx.x;
  if (idx >= K*N) return;
  float v;
  if (mode == 0){
    int n = idx / K, k = idx - n*K;
    v = src[k*N + n];
  } else if (mode == 1){
    int j = idx & 7, lv = (idx >> 3) & 63, ks = (idx >> 9) & 7, nb = idx >> 12;
    int o = nb*32 + (lv & 31), k = ks*16 + (lv >> 5)*8 + j;
    v = src[k*128 + o];
  } else {
    int j = idx & 7, lv = (idx >> 3) & 63, ks = (idx >> 9) & 3, nb = idx >> 11;
    int o = nb*32 + (lv & 31), k = ks*16 + (lv >> 5)*8 + j;
    v = src[k*128 + o];
  }
  p.dst[doff + idx] = f2b(v);
}

// elementwise fp32 -> bf16
__global__ void __launch_bounds__(256) k_f2b(
    const float* __restrict__ src, u16* __restrict__ dst, int n)
{
  int i = blockIdx.x*256 + threadIdx.x;
  if (i < n) dst[i] = f2b(src[i]);
}

// rbf2[e,h] = ((rbf @ W_rbf1) @ W_rbf2)[e,h]
__global__ void __launch_bounds__(256) k_rbf(
    const float* __restrict__ rbf, const float* __restrict__ W1,
    const float* __restrict__ W2, u16* __restrict__ out, int E)
{
  __shared__ float w1s[48];
  __shared__ float w2s[1024];
  for (int i = threadIdx.x; i < 48;   i += 256) w1s[i] = W1[i];
  for (int i = threadIdx.x; i < 1024; i += 256) w2s[i] = W2[i];
  __syncthreads();
  int idx = blockIdx.x*256 + threadIdx.x;
  if (idx >= E*128) return;
  int e = idx >> 7, h = idx & 127;
  float rv[6];
#pragma unroll
  for (int k = 0; k < 6; k++) rv[k] = rbf[e*6 + k];
  float o = 0.f;
#pragma unroll
  for (int j = 0; j < 8; j++){
    float m = 0.f;
#pragma unroll
    for (int k = 0; k < 6; k++) m += rv[k] * w1s[k*8 + j];
    o += m * w2s[j*128 + h];
  }
  out[idx] = f2b(o);
}

// s1[t,0:8] = (sbf @ W_sbf1)[t]
__global__ void __launch_bounds__(256) k_s1(
    const float* __restrict__ sbf, const float* __restrict__ W1,
    float* __restrict__ s1, int T)
{
  __shared__ float w1s[336];
  for (int i = threadIdx.x; i < 336; i += 256) w1s[i] = W1[i];
  __syncthreads();
  int t = blockIdx.x*256 + threadIdx.x;
  if (t >= T) return;
  const float* row = sbf + (size_t)t*42;
  float a[8];
#pragma unroll
  for (int j = 0; j < 8; j++) a[j] = 0.f;
  for (int k = 0; k < 42; k++){
    float sv = row[k];
#pragma unroll
    for (int j = 0; j < 8; j++) a[j] += sv * w1s[k*8 + j];
  }
#pragma unroll
  for (int j = 0; j < 8; j++) s1[(size_t)t*8 + j] = a[j];
}

// one wave per triplet: sbf_e = s1 @ W_sbf2; v = x_kj[idx_kj]*sbf_e; scatter into agg[branch]
__global__ void __launch_bounds__(256) k_triplet(
    const int* __restrict__ idx_kj, const int* __restrict__ idx_ji,
    const int* __restrict__ bt, const float* __restrict__ s1,
    const float* __restrict__ Wsbf2, const u16* __restrict__ xkj,
    float* __restrict__ agg, int T, int E)
{
  int g = blockIdx.x*256 + threadIdx.x;
  int t = g >> 6, lane = g & 63;
  if (t >= T) return;
  int kj = idx_kj[t], ji = idx_ji[t];
  int b = bt[kj] + 1;
  b = b < 0 ? 0 : (b > 5 ? 5 : b);
  float se = 0.f;
#pragma unroll
  for (int j = 0; j < 8; j++) se += s1[(size_t)t*8 + j] * Wsbf2[j*64 + lane];
  float v = b2f(xkj[(size_t)kj*64 + lane]) * se;
  unsafeAtomicAdd(&agg[((size_t)b*E + ji)*64 + lane], v);
}

// agg fp32 -> aggb bf16 slots 0..5, slot 6 = sum (== agg_gen)
__global__ void __launch_bounds__(256) k_cvt(
    const float* __restrict__ agg, u16* __restrict__ aggb, int EI)
{
  int idx = blockIdx.x*256 + threadIdx.x;
  if (idx >= EI) return;
  float s = 0.f;
#pragma unroll
  for (int b = 0; b < 6; b++){
    float v = agg[(size_t)b*EI + idx];
    s += v;
    aggb[(size_t)b*EI + idx] = f2b(v);
  }
  aggb[(size_t)6*EI + idx] = f2b(s);
}

// reduce nsl slices of S into out (fp32)
__global__ void __launch_bounds__(256) k_red(
    const u16* __restrict__ S, const float* __restrict__ alphaP,
    float* __restrict__ out, size_t EH, int nsl, int genLast, int accum)
{
  size_t base = ((size_t)blockIdx.x*256 + threadIdx.x)*4;
  if (base >= EH) return;
  float al = alphaP[0];
  float s0=0,s1=0,s2=0,s3=0;
  for (int c = 0; c < nsl; c++){
    float sc = (genLast && c == nsl-1) ? al : (1.f - al);
    ushort4 v = *(const ushort4*)&S[(size_t)c*EH + base];
    s0 += sc*b2f(v.x); s1 += sc*b2f(v.y); s2 += sc*b2f(v.z); s3 += sc*b2f(v.w);
  }
  float4 o;
  if (accum){
    float4 p = *(const float4*)&out[base];
    o.x = p.x + s0; o.y = p.y + s1; o.z = p.z + s2; o.w = p.w + s3;
  } else {
    o.x = s0; o.y = s1; o.z = s2; o.w = s3;
  }
  *(float4*)&out[base] = o;
}

// ================== batched fused-epilogue MFMA GEMM (pre-chain) ==================
template<int MODE, int N, int K>
__global__ void __launch_bounds__(256) k_gemmb(
    const u16* __restrict__ A, size_t aStr,
    const u16* __restrict__ WTp, int wStr,
    const float* __restrict__ bias, int bStr,
    const u16* __restrict__ aux, size_t xStr,
    u16* __restrict__ out, size_t oStr,
    int cBase, int M)
{
  constexpr int KP = K + 8;
  constexpr int PITCH = N + 4;
  constexpr size_t SW = (size_t)KP*N*2;
  constexpr size_t SE = (size_t)64*PITCH*4;
  constexpr size_t SMEM = SW > SE ? SW : SE;
  __shared__ __attribute__((aligned(16))) char smem[SMEM];
  u16*   wlds = (u16*)smem;
  float* elds = (float*)smem;

  const int tid = threadIdx.x;
  const int sl = blockIdx.y;
  const int c = cBase + sl;
  const int wsel = c < 5 ? c : 5;
  const u16* __restrict__ Ac = A + (size_t)sl*aStr;
  const u16* __restrict__ Wc = WTp + (size_t)wsel*wStr;
  const u16* __restrict__ auxc = aux ? aux + (size_t)sl*xStr : (const u16*)0;
  u16* __restrict__ outc = out + (size_t)sl*oStr;

  constexpr int CH = (N*K)/8;
  for (int ch = tid; ch < CH; ch += 256){
    int n  = ch / (K/8);
    int kc = (ch - n*(K/8))*8;
    *(int4*)&wlds[n*KP + kc] = *(const int4*)&Wc[n*K + kc];
  }
  __syncthreads();

  const int wave = tid >> 6, lane = tid & 63;
  const int lr = lane & 15, lq = lane >> 4;
  const int m0 = blockIdx.x*128 + wave*32;
  constexpr int NBN = N/16;
  f32x4 acc[2][NBN];
#pragma unroll
  for (int i = 0; i < 2; i++)
#pragma unroll
    for (int j = 0; j < NBN; j++) acc[i][j] = (f32x4){0.f,0.f,0.f,0.f};

  const int r0 = m0 + lr;
#pragma unroll
  for (int ks = 0; ks < K/32; ks++){
    const int k0 = ks*32 + lq*8;
    bfrag a0 = {0,0,0,0,0,0,0,0}, a1 = {0,0,0,0,0,0,0,0};
    if (r0 < M)      a0 = *(const bfrag*)&Ac[(size_t)r0*K + k0];
    if (r0 + 16 < M) a1 = *(const bfrag*)&Ac[(size_t)(r0+16)*K + k0];
#pragma unroll
    for (int nb = 0; nb < NBN; nb++){
      bfrag bv = *(const bfrag*)&wlds[(nb*16 + lr)*KP + k0];
      acc[0][nb] = __builtin_amdgcn_mfma_f32_16x16x32_bf16(a0, bv, acc[0][nb], 0, 0, 0);
      acc[1][nb] = __builtin_amdgcn_mfma_f32_16x16x32_bf16(a1, bv, acc[1][nb], 0, 0, 0);
    }
  }

  float bv[NBN];
#pragma unroll
  for (int nb = 0; nb < NBN; nb++)
    bv[nb] = bias ? bias[wsel*bStr + nb*16 + lr] : 0.f;

#pragma unroll
  for (int mb = 0; mb < 2; mb++){
    __syncthreads();
#pragma unroll
    for (int nb = 0; nb < NBN; nb++){
      const int col = nb*16 + lr;
#pragma unroll
      for (int r = 0; r < 4; r++){
        float v = silu_f(acc[mb][nb][r] + bv[nb]);
        elds[(wave*16 + lq*4 + r)*PITCH + col] = v;
      }
    }
    __syncthreads();
    constexpr int CHUNKS = 64*N/4;
    for (int q = tid; q < CHUNKS; q += 256){
      int lrow = q / (N/4);
      int col0 = (q - lrow*(N/4))*4;
      int w = lrow >> 4, rr = lrow & 15;
      int grow = blockIdx.x*128 + w*32 + mb*16 + rr;
      if (grow >= M) continue;
      float4 v = *(float4*)&elds[lrow*PITCH + col0];
      size_t oi = (size_t)grow*N + col0;
      float o0 = v.x, o1 = v.y, o2 = v.z, o3 = v.w;
      if (MODE == 0){
        ushort4 av = *(const ushort4*)&auxc[oi];
        o0 *= b2f(av.x); o1 *= b2f(av.y); o2 *= b2f(av.z); o3 *= b2f(av.w);
      } else if (auxc){
        ushort4 av = *(const ushort4*)&auxc[oi];
        o0 += b2f(av.x); o1 += b2f(av.y); o2 += b2f(av.z); o3 += b2f(av.w);
      }
      ushort4 ov; ov.x = f2b(o0); ov.y = f2b(o1); ov.z = f2b(o2); ov.w = f2b(o3);
      *(ushort4*)&outc[oi] = ov;
    }
  }
}

// ================== register-tile chain, LDS-staged weights ==================
// grid (ceil(E/128), 7), 256 threads = 4 waves x 32 rows.
// R4 VALU diet over R3 (which was VALU-issue-bound at 71% VALUBusy):
//  - silu via v_rcp (was IEEE div: 10+ instr each, 64/stage)
//  - bias pre-seeded into MFMA C-in (removes 64 v_add/stage)
//  - repack via v_permlane32_swap_b32: one swap yields BOTH halves
//    (replaces 4 ds_bpermute + 4 cndmask per ks with 2 permlane)
__global__ void __launch_bounds__(256, 2) k_chain(
    const u16* __restrict__ XB, const u16* __restrict__ AGGB,
    const u16* __restrict__ WTb,
    const float* __restrict__ bji, const float* __restrict__ bbs1,
    const float* __restrict__ bbs2, const float* __restrict__ blin,
    const float* __restrict__ bas1, const float* __restrict__ bas2,
    u16* __restrict__ OUT, int E)
{
  __shared__ __attribute__((aligned(16))) u16 wbuf[2][16384];   // 64 KB

  const int tid = threadIdx.x;
  const int wave = tid >> 6, l = tid & 63;
  const int hi = l >> 5;
  const int sl = blockIdx.y;
  const int b  = sl < 5 ? sl : 5;
  const size_t EH = (size_t)E*128, EI = (size_t)E*64;
  const int row = blockIdx.x*128 + wave*32 + (l & 31);
  const bool rok = row < E;
  const size_t rb = (size_t)(rok ? row : 0);    // clamp OOB rows to row 0 (never stored)

  const f32x16 Z = {0,0,0,0,0,0,0,0,0,0,0,0,0,0,0,0};
  f32x16 acc[4];      // acc[nb]: 32 features x 32 rows quadrant
  u32x4  fr[8];       // tile B-frags: fr[ks] = T[m][ks*16 + hi*8 + j]
  uint32_t pkv[4][8]; // packed bf16 pairs of current stage output (acc-reg order)
  uint32_t res[4][8]; // saved residual (t1 / h / h2 by phase)

  // stage weights (nch x 1KB chunks) into wbuf[bufi] via async global->LDS.
  auto stageW = [&](const u16* Wg, int nch, int bufi){
    for (int i = wave; i < nch; i += 4){
      const u16* g = Wg + i*512 + l*8;
      __builtin_amdgcn_global_load_lds(
          (const __attribute__((address_space(1))) void*)g,
          (__attribute__((address_space(3))) void*)&wbuf[bufi][i*512],
          16, 0, 0);
    }
  };

  // seed acc with bias in acc-register layout: acc[nb][r] = bias[nb*32 + (r&3) + 8*(r>>2) + 4*hi]
  auto seedB = [&](const float* __restrict__ bp){
#pragma unroll
    for (int nb = 0; nb < 4; nb++){
      float4 bd0 = *(const float4*)&bp[nb*32 +  0 + 4*hi];
      float4 bd1 = *(const float4*)&bp[nb*32 +  8 + 4*hi];
      float4 bd2 = *(const float4*)&bp[nb*32 + 16 + 4*hi];
      float4 bd3 = *(const float4*)&bp[nb*32 + 24 + 4*hi];
      acc[nb] = (f32x16){bd0.x,bd0.y,bd0.z,bd0.w, bd1.x,bd1.y,bd1.z,bd1.w,
                         bd2.x,bd2.y,bd2.z,bd2.w, bd3.x,bd3.y,bd3.z,bd3.w};
    }
  };

  auto gemm128L = [&](int bufi){
#pragma unroll
    for (int ks = 0; ks < 8; ks++)
#pragma unroll
      for (int nb = 0; nb < 4; nb++){
        bfrag w = *(const bfrag*)&wbuf[bufi][((nb*8 + ks)*64 + l)*8];
        acc[nb] = __builtin_amdgcn_mfma_f32_32x32x16_bf16(
            w, __builtin_bit_cast(bfrag, fr[ks]), acc[nb], 0, 0, 0);
      }
  };

  // acc/pkv -> fr for next stage. One v_permlane32_swap_b32 per value pair:
  // swap(pA,pB) -> ( {lo:pA.lo, hi:pB.lo}, {lo:pA.hi, hi:pB.hi} ) = (f.lo_j, f.hi_j)
  auto repack = [&]{
#pragma unroll
    for (int ks = 0; ks < 8; ks++){
      const int nb = ks >> 1, g0 = (ks & 1)*4;
      u32x2 r0 = __builtin_amdgcn_permlane32_swap(pkv[nb][g0+0], pkv[nb][g0+2], false, false);
      u32x2 r1 = __builtin_amdgcn_permlane32_swap(pkv[nb][g0+1], pkv[nb][g0+3], false, false);
      u32x4 f; f.x = r0.x; f.y = r1.x; f.z = r0.y; f.w = r1.y;
      fr[ks] = f;
    }
  };

  // epilogue (bias already in acc): mode 0 = silu(a); 1 = silu(a)+res, res=pkv;
  // 2 = silu(a)+x, res=pkv
  auto epi = [&](int mode){
#pragma unroll
    for (int nb = 0; nb < 4; nb++){
      uint2 xv0, xv1, xv2, xv3;
      if (mode == 2){
        xv0 = *(const uint2*)&XB[rb*128 + nb*32 +  0 + 4*hi];
        xv1 = *(const uint2*)&XB[rb*128 + nb*32 +  8 + 4*hi];
        xv2 = *(const uint2*)&XB[rb*128 + nb*32 + 16 + 4*hi];
        xv3 = *(const uint2*)&XB[rb*128 + nb*32 + 24 + 4*hi];
      }
#pragma unroll
      for (int g = 0; g < 8; g++){
        float v0 = silu_f(acc[nb][2*g]);
        float v1 = silu_f(acc[nb][2*g+1]);
        if (mode == 1){ v0 += lo16(res[nb][g]); v1 += hi16(res[nb][g]); }
        if (mode == 2){
          const int d = g >> 1, s = g & 1;
          uint2 xd2 = d==0 ? xv0 : d==1 ? xv1 : d==2 ? xv2 : xv3;
          uint32_t xd = s ? xd2.y : xd2.x;
          v0 += lo16(xd); v1 += hi16(xd);
        }
        pkv[nb][g] = cvtpk(v0, v1);
      }
      if (mode != 0){
#pragma unroll
        for (int g = 0; g < 8; g++) res[nb][g] = pkv[nb][g];
      }
    }
  };

  // ---- prologue: W_up (16KB) -> buf0 ----
  stageW(WTb + OFF_UP + b*8192, 16, 0);
  __syncthreads();                         // vmcnt drain: W_up ready

  // ---- S1: t1 = silu(agg_sl @ W_up)  [K=64, no bias] -> res ----
  {
#pragma unroll
    for (int ks = 0; ks < 4; ks++)
      fr[ks] = *(const u32x4*)&AGGB[(size_t)sl*EI + rb*64 + ks*16 + hi*8];
    stageW(WTb + OFF_JI + b*16384, 32, 1); // prefetch W_ji
#pragma unroll
    for (int nb = 0; nb < 4; nb++) acc[nb] = Z;
#pragma unroll
    for (int ks = 0; ks < 4; ks++)
#pragma unroll
      for (int nb = 0; nb < 4; nb++){
        bfrag w = *(const bfrag*)&wbuf[0][((nb*4 + ks)*64 + l)*8];
        acc[nb] = __builtin_amdgcn_mfma_f32_32x32x16_bf16(
            w, __builtin_bit_cast(bfrag, fr[ks]), acc[nb], 0, 0, 0);
      }
#pragma unroll
    for (int nb = 0; nb < 4; nb++)
#pragma unroll
      for (int g = 0; g < 8; g++)
        res[nb][g] = cvtpk(silu_f(acc[nb][2*g]), silu_f(acc[nb][2*g+1]));
  }
  __syncthreads();                         // W_ji ready; all waves done with buf0

  // ---- S2: h = silu(x @ W_ji + bji) + t1 ----
#pragma unroll
  for (int ks = 0; ks < 8; ks++)
    fr[ks] = *(const u32x4*)&XB[rb*128 + ks*16 + hi*8];
  stageW(WTb + OFF_BS1 + b*16384, 32, 0);  // prefetch W_bs1
  seedB(bji + b*128);
  gemm128L(1);
  epi(1);
  repack();
  __syncthreads();

  // ---- S3: t = silu(h @ W_bs1 + bbs1) ----
  stageW(WTb + OFF_BS2 + b*16384, 32, 1);
  seedB(bbs1 + b*128);
  gemm128L(0);
  epi(0);
  repack();
  __syncthreads();

  // ---- S4: h = h + silu(t @ W_bs2 + bbs2) ----
  stageW(WTb + OFF_LIN + b*16384, 32, 0);
  seedB(bbs2 + b*128);
  gemm128L(1);
  epi(1);
  repack();
  __syncthreads();

  // ---- S5: h2 = silu(h @ W_lin + blin) + x ----
  stageW(WTb + OFF_AS1 + b*16384, 32, 1);
  seedB(blin + b*128);
  gemm128L(0);
  epi(2);
  repack();
  __syncthreads();

  // ---- S6: t2 = silu(h2 @ W_as1 + bas1) ----
  stageW(WTb + OFF_AS2 + b*16384, 32, 0);
  seedB(bas1 + b*128);
  gemm128L(1);
  epi(0);
  repack();
  __syncthreads();

  // ---- S7: out = h2 + silu(t2 @ W_as2 + bas2) ----
  seedB(bas2 + b*128);
  gemm128L(0);
  epi(1);
  if (rok){
    const size_t ob = (size_t)sl*EH + (size_t)row*128;
#pragma unroll
    for (int nb = 0; nb < 4; nb++)
#pragma unroll
      for (int d = 0; d < 4; d++){
        uint2 o; o.x = pkv[nb][2*d]; o.y = pkv[nb][2*d+1];
        *(uint2*)&OUT[ob + nb*32 + d*8 + 4*hi] = o;
      }
  }
}

extern "C" void kernel_launch(void* const* d_in, const int* in_sizes, int n_in,
                              void* d_out, int out_size, void* d_ws, size_t ws_size,
                              hipStream_t stream)
{
  const float* x     = (const float*)d_in[0];
  const float* rbf   = (const float*)d_in[1];
  const float* sbf   = (const float*)d_in[2];
  const int*   ikj   = (const int*)d_in[3];
  const int*   iji   = (const int*)d_in[4];
  const int*   bt    = (const int*)d_in[5];
  const float* alphaP= (const float*)d_in[6];
  const float* Wrbf1 = (const float*)d_in[8];
  const float* Wrbf2 = (const float*)d_in[9];
  const float* Wsbf1 = (const float*)d_in[10];
  const float* Wsbf2 = (const float*)d_in[11];
  const float* Wkj   = (const float*)d_in[12];
  const float* bkj   = (const float*)d_in[13];
  const float* Wji   = (const float*)d_in[14];
  const float* bji   = (const float*)d_in[15];
  const float* Wdown = (const float*)d_in[16];
  const float* Wup   = (const float*)d_in[17];
  const float* Wbs1  = (const float*)d_in[18];
  const float* bbs1  = (const float*)d_in[19];
  const float* Wbs2  = (const float*)d_in[20];
  const float* bbs2  = (const float*)d_in[21];
  const float* Wlin  = (const float*)d_in[22];
  const float* blin  = (const float*)d_in[23];
  const float* Was1  = (const float*)d_in[24];
  const float* bas1  = (const float*)d_in[25];
  const float* Was2  = (const float*)d_in[26];
  const float* bas2  = (const float*)d_in[27];

  const int E = in_sizes[5];
  const int T = in_sizes[3];
  const int H = 128, I = 64;
  const size_t EH = (size_t)E*H, EI = (size_t)E*I;
  const int mt = (E + 127)/128;

  TW tw{Wkj, Wdown, Wji, Wup, Wbs1, Wbs2, Wlin, Was1, Was2, (u16*)0};

  char* ws = (char*)d_ws;
  size_t off = 0;
  auto arena = [&](size_t bytes)->size_t{
    size_t o = off; off += (bytes + 255) & ~(size_t)255; return o;
  };
  size_t oWT   = arena((size_t)WT_TOTAL*2);   // 1.33 MB
  size_t oXB   = arena(EH*2);                 // 25.6 MB
  size_t oXKJ  = arena(EI*2);                 // 12.8 MB
  size_t oAGGB = arena(7*EI*2);               // 89.6 MB
  size_t oBUF  = arena(2*(4*EH*2));           // 204.8 MB
  // pre-chain aliases inside BUF:
  //   AGG  fp32 6*EI*4 at BUF+0          (dead after k_cvt)
  //   S1   fp32 T*8*4  at BUF+153.6MB    (dead after k_triplet)
  //   RBF2 bf16 EH*2   at BUF+0          (dead after KJ)
  //   TMP  bf16 EH*2   at BUF+172.8MB    (dead after DOWN)
  // chain: OUT bf16 7*EH*2 = 179.2 MB at BUF+0
  if (off > ws_size) return;

  u16*   WTb  = (u16*)(ws + oWT);
  u16*   XB   = (u16*)(ws + oXB);
  u16*   XKJ  = (u16*)(ws + oXKJ);
  u16*   AGGB = (u16*)(ws + oAGGB);
  char*  BUF  = ws + oBUF;
  u16*   OUT  = (u16*)BUF;
  float* AGG  = (float*)BUF;
  float* S1   = (float*)(BUF + 6*EI*4);
  u16*   RBF2 = (u16*)BUF;
  u16*   TMP  = (u16*)(BUF + 6*EI*4 + (size_t)T*8*4);

  tw.dst = WTb;
  hipLaunchKernelGGL(k_transpose, dim3(64, 44, 1), dim3(256, 1, 1), 0, stream, tw);
  k_f2b<<<dim3((int)((EH + 255)/256)), dim3(256), 0, stream>>>(x, XB, (int)EH);
  k_rbf<<<dim3((int)((EH + 255)/256)), dim3(256), 0, stream>>>(rbf, Wrbf1, Wrbf2, RBF2, E);
  // t = silu(x@W_kj+b)*rbf2 -> TMP
  k_gemmb<0,128,128><<<dim3(mt,1), dim3(256), 0, stream>>>(XB,0, WTb+OFF_KJ,0, bkj,0, RBF2,0, TMP,0, 0, E);
  // x_kj = silu(t@W_down) -> XKJ
  k_gemmb<1,64,128><<<dim3(mt,1), dim3(256), 0, stream>>>(TMP,0, WTb+OFF_DOWN,0, (const float*)0,0, (const u16*)0,0, XKJ,0, 0, E);
  k_s1<<<dim3((T + 255)/256), dim3(256), 0, stream>>>(sbf, Wsbf1, S1, T);
  hipMemsetAsync(BUF, 0, 6*EI*4, stream);
  k_triplet<<<dim3((int)(((size_t)T*64 + 255)/256)), dim3(256), 0, stream>>>(ikj, iji, bt, S1, Wsbf2, XKJ, AGG, T, E);
  k_cvt<<<dim3((int)((EI + 255)/256)), dim3(256), 0, stream>>>(AGG, AGGB, (int)EI);

  // register-tile chain with LDS-staged weights: one dispatch, 7 slices x 7 GEMMs
  k_chain<<<dim3(mt, 7), dim3(256), 0, stream>>>(XB, AGGB, WTb,
      bji, bbs1, bbs2, blin, bas1, bas2, OUT, E);
  // fold all 7 slices into d_out (slice 6 = generic -> alpha)
  k_red<<<dim3((int)((EH/4 + 255)/256)), dim3(256), 0, stream>>>(OUT, alphaP, (float*)d_out, EH, 7, 1, 0);
  (void)n_in; (void)out_size;
}